// Round 5
// baseline (2358.644 us; speedup 1.0000x reference)
//
#include <hip/hip_runtime.h>

// ---- problem constants ----
#define BT      32768     // B*T = 128*256
#define T_SEQ   256
#define E_DIM   384
#define NH      6
#define NL      6
#define VOC     65
#define FF_DIM  1536
#define QKV_N   1152      // 3*E

typedef short bf16x8 __attribute__((ext_vector_type(8)));   // 8 bf16 (4 VGPRs)
typedef float f32x4  __attribute__((ext_vector_type(4)));
typedef unsigned short u16;

typedef const unsigned int __attribute__((address_space(1))) gu32;
typedef unsigned int       __attribute__((address_space(3))) lu32;

__device__ __forceinline__ u16 f2bf(float x) {              // RNE fp32->bf16
  unsigned u = __builtin_bit_cast(unsigned, x);
  u += 0x7fffu + ((u >> 16) & 1u);
  return (u16)(u >> 16);
}
__device__ __forceinline__ float bf2f(u16 v) {
  unsigned u = ((unsigned)v) << 16;
  return __builtin_bit_cast(float, u);
}

__device__ __forceinline__ void load_lds_16(const void* g, void* l) {
  __builtin_amdgcn_global_load_lds((gu32*)g, (lu32*)l, 16, 0, 0);
}

// ---------------- unified LDS-tiled transpose: src[b][R][C] fp32 -> dst bf16 [.. C][R] ----------------
__global__ __launch_bounds__(256) void transpose_t(
    const float* __restrict__ src, u16* __restrict__ dst, int R, int C,
    long sbs, long dbs_outer, int inner, long dbs_inner, long dbase) {
  __shared__ float t[32][33];
  const int b = blockIdx.z;
  const float* s = src + (long)b * sbs;
  u16* d = dst + dbase + (long)(b / inner) * dbs_outer + (long)(b % inner) * dbs_inner;
  const int r0 = blockIdx.x * 32, c0 = blockIdx.y * 32;
  const int tx = threadIdx.x & 31, ty = threadIdx.x >> 5;   // 32 x 8
#pragma unroll
  for (int i = 0; i < 4; i++) {
    int rr = ty + i * 8;
    int r = r0 + rr, c = c0 + tx;
    if (r < R && c < C) t[rr][tx] = s[(long)r * C + c];
  }
  __syncthreads();
#pragma unroll
  for (int i = 0; i < 4; i++) {
    int cc = ty + i * 8;
    int c = c0 + cc, r = r0 + tx;
    if (c < C && r < R) d[(long)c * R + r] = f2bf(t[tx][cc]);
  }
}

// ---------------- embedding (bf16 out) ----------------
__global__ __launch_bounds__(256) void embed_k(const int* __restrict__ idx,
                                               const float* __restrict__ tok,
                                               const float* __restrict__ pos,
                                               u16* __restrict__ x) {
  int i = blockIdx.x * 256 + threadIdx.x;        // over BT*48 groups of 8
  int bt = i / 48, q = i - bt * 48;
  int t = bt & 255;
  const float4* tp = (const float4*)(tok + (size_t)idx[bt] * E_DIM + q * 8);
  const float4* pp = (const float4*)(pos + (size_t)t * E_DIM + q * 8);
  float4 a0 = tp[0], a1 = tp[1], p0 = pp[0], p1 = pp[1];
  u16 o[8];
  o[0] = f2bf(a0.x + p0.x); o[1] = f2bf(a0.y + p0.y);
  o[2] = f2bf(a0.z + p0.z); o[3] = f2bf(a0.w + p0.w);
  o[4] = f2bf(a1.x + p1.x); o[5] = f2bf(a1.y + p1.y);
  o[6] = f2bf(a1.z + p1.z); o[7] = f2bf(a1.w + p1.w);
  *(bf16x8*)(x + (size_t)bt * E_DIM + q * 8) = *(bf16x8*)o;
}

// ---------------- layernorm (bf16 in -> bf16 out, fp32 math) ----------------
__global__ __launch_bounds__(256) void ln_k(const u16* __restrict__ x,
                                            const float* __restrict__ gam,
                                            const float* __restrict__ bet,
                                            u16* __restrict__ out) {
  int tid = threadIdx.x, lane = tid & 63, w = tid >> 6;
  size_t token = (size_t)blockIdx.x * 4 + w;
  const u16* xr = x + token * E_DIM;
  u16 raw[6];
  *(uint2*)raw          = *(const uint2*)(xr + 4 * lane);
  *(unsigned*)(raw + 4) = *(const unsigned*)(xr + 256 + 2 * lane);
  float v[6]; float s = 0.f;
#pragma unroll
  for (int i = 0; i < 6; i++) { v[i] = bf2f(raw[i]); s += v[i]; }
#pragma unroll
  for (int d = 1; d < 64; d <<= 1) s += __shfl_xor(s, d);
  float mean = s * (1.f / E_DIM);
  float q = 0.f;
#pragma unroll
  for (int i = 0; i < 6; i++) { float d0 = v[i] - mean; q += d0 * d0; }
#pragma unroll
  for (int d = 1; d < 64; d <<= 1) q += __shfl_xor(q, d);
  float r = rsqrtf(q * (1.f / E_DIM) + 1e-5f);
  int e[6] = {4 * lane, 4 * lane + 1, 4 * lane + 2, 4 * lane + 3,
              256 + 2 * lane, 256 + 2 * lane + 1};
  u16 o[6];
#pragma unroll
  for (int i = 0; i < 6; i++)
    o[i] = f2bf((v[i] - mean) * r * gam[e[i]] + bet[e[i]]);
  u16* orow = out + token * E_DIM;
  *(uint2*)(orow + 4 * lane)          = *(uint2*)o;
  *(unsigned*)(orow + 256 + 2 * lane) = *(unsigned*)(o + 4);
}

// ---------------- hybrid MFMA GEMM: C = A[M][K] @ Bt[N][K]^T (bf16) ----------------
// R5: A staged via 3-buffer counted-vmcnt DMA (2 DMA/step, LDS 24 KB -> LDS allows
// 6 blocks/CU); B (weights, L2-resident, reused by all 256 m-blocks) streamed DIRECT
// from global into a depth-1 register double-buffer (bfA/bfB, NK always even).
// Static per-step issue order (4 B-loads -> sched_barrier -> 2 A-DMAs) makes the
// mixed vmcnt accounting exact: end-of-step `s_waitcnt vmcnt(4+2*aPf)` retires
// exactly the next step's A buffer while newer loads stay in flight; never drains
// to 0 mid-loop. Compiler auto-waits cover the B register deps. setprio(1) around
// the MFMA cluster (waves have load-issue vs MFMA role diversity). Epilogue = R0's
// proven LDS-staged transpose writeback (full-line uint2 stores).
__global__ __launch_bounds__(256) void gemm_d(
    const u16* __restrict__ A, const u16* __restrict__ Bt, int K, int Nstore,
    const float* __restrict__ bias, const u16* __restrict__ resid,
    u16* __restrict__ outH, float* __restrict__ outF, int relu) {
  __shared__ u16 smem[12288];                 // As[3][128][32]; epilogue reuses front
  const int tid = threadIdx.x, lane = tid & 63, wv = tid >> 6;
  const int quad = lane >> 4, l16 = lane & 15;
  const int m0 = blockIdx.x * 128, n0 = blockIdx.y * 128;
  const int wm = (wv & 1) * 64, wn = (wv >> 1) * 64;

  const int lrow = lane >> 2;                        // within-group row 0..15
  const int lchunk = (lane & 3) ^ ((lane >> 3) & 3); // swizzled source chunk

  f32x4 acc[4][4];
#pragma unroll
  for (int i = 0; i < 4; i++)
#pragma unroll
    for (int j = 0; j < 4; j++) acc[i][j] = (f32x4){0.f, 0.f, 0.f, 0.f};

  auto stageA = [&](int sel, int k0) {               // 2 VMEM ops per call
#pragma unroll
    for (int j = 0; j < 2; j++) {
      int rid = wv * 2 + j;                          // 8 groups of 16 rows
      int r = rid * 16 + lrow;
      load_lds_16(A + (size_t)(m0 + r) * K + k0 + lchunk * 8, &smem[sel * 4096 + rid * 512]);
    }
  };
  const u16* Bw = Bt + (size_t)(n0 + wn + l16) * K + quad * 8;  // per-lane B base
  auto loadB = [&](bf16x8* dst, int kt) {            // 4 VMEM ops per call
#pragma unroll
    for (int j = 0; j < 4; j++)
      dst[j] = *(const bf16x8*)(Bw + (size_t)j * 16 * K + kt * 32);
  };

  const int NK = K >> 5;                       // even (12 or 48) at every call site
  bf16x8 bfA[4], bfB[4];
  loadB(bfA, 0);
  __builtin_amdgcn_sched_barrier(0);
  stageA(0, 0);
  stageA(1, 32);
  asm volatile("s_waitcnt vmcnt(2)" ::: "memory");   // retire B(0)+bufA0; bufA1 in flight
  __builtin_amdgcn_s_barrier();

  const int slot = (quad ^ ((l16 >> 1) & 3)) * 8;    // un-swizzle for fragment read
  int cur = 0, stg = 2;
  for (int kt = 0; kt < NK; kt += 2) {
    // ---- step kt (uses bfA) ----
    loadB(bfB, kt + 1);                              // kt+1 <= NK-1 always
    __builtin_amdgcn_sched_barrier(0);
    bool aPf = (kt + 2 < NK);
    if (aPf) { stageA(stg, (kt + 2) * 32); if (++stg == 3) stg = 0; }
    {
      const u16* Ab = &smem[cur * 4096];
      bf16x8 af[4];
#pragma unroll
      for (int i = 0; i < 4; i++) af[i] = *(const bf16x8*)&Ab[(wm + i * 16 + l16) * 32 + slot];
      __builtin_amdgcn_s_setprio(1);
#pragma unroll
      for (int i = 0; i < 4; i++)
#pragma unroll
        for (int j = 0; j < 4; j++)
          acc[i][j] = __builtin_amdgcn_mfma_f32_16x16x32_bf16(af[i], bfA[j], acc[i][j], 0, 0, 0);
      __builtin_amdgcn_s_setprio(0);
    }
    if (aPf) asm volatile("s_waitcnt vmcnt(6)" ::: "memory");  // retire bufA(kt+1)
    else     asm volatile("s_waitcnt vmcnt(4)" ::: "memory");
    __builtin_amdgcn_s_barrier();
    if (++cur == 3) cur = 0;

    // ---- step kt+1 (uses bfB) ----
    if (aPf) loadB(bfA, kt + 2);
    __builtin_amdgcn_sched_barrier(0);
    bool aPf2 = (kt + 3 < NK);
    if (aPf2) { stageA(stg, (kt + 3) * 32); if (++stg == 3) stg = 0; }
    {
      const u16* Ab = &smem[cur * 4096];
      bf16x8 af[4];
#pragma unroll
      for (int i = 0; i < 4; i++) af[i] = *(const bf16x8*)&Ab[(wm + i * 16 + l16) * 32 + slot];
      __builtin_amdgcn_s_setprio(1);
#pragma unroll
      for (int i = 0; i < 4; i++)
#pragma unroll
        for (int j = 0; j < 4; j++)
          acc[i][j] = __builtin_amdgcn_mfma_f32_16x16x32_bf16(af[i], bfB[j], acc[i][j], 0, 0, 0);
      __builtin_amdgcn_s_setprio(0);
    }
    {
      int nOut = (aPf ? 4 : 0) + (aPf2 ? 2 : 0);     // B(kt+2) + bufA(kt+3) in flight
      if (nOut == 6)      asm volatile("s_waitcnt vmcnt(6)" ::: "memory");
      else if (nOut == 4) asm volatile("s_waitcnt vmcnt(4)" ::: "memory");
      else                asm volatile("s_waitcnt vmcnt(0)" ::: "memory");
    }
    __builtin_amdgcn_s_barrier();
    if (++cur == 3) cur = 0;
  }

  if (outH) {
#pragma unroll
    for (int p = 0; p < 4; p++) {
      if (p) __syncthreads();
      if ((wv >> 1) == (p >> 1)) {
#pragma unroll
        for (int jj = 0; jj < 2; jj++) {
          int j = (p & 1) * 2 + jj;
          int gn = n0 + wn + j * 16 + l16;
          float bv = bias ? bias[gn] : 0.f;
          int lcol = jj * 16 + l16;
#pragma unroll
          for (int i = 0; i < 4; i++)
#pragma unroll
            for (int r = 0; r < 4; r++) {
              float v = acc[i][j][r] + bv;
              if (relu) v = fmaxf(v, 0.f);
              smem[(wm + i * 16 + quad * 4 + r) * 36 + lcol] = f2bf(v);
            }
        }
      }
      __syncthreads();
      const int gc0 = n0 + p * 32;
#pragma unroll
      for (int s = 0; s < 4; s++) {
        int row = s * 32 + (tid >> 3);
        int seg = (tid & 7) * 4;
        u16 pk[4];
        *(uint2*)pk = *(const uint2*)&smem[row * 36 + seg];
        size_t o = (size_t)(m0 + row) * Nstore + gc0 + seg;
        if (resid) {
          u16 rv[4];
          *(uint2*)rv = *(const uint2*)&resid[o];
#pragma unroll
          for (int q2 = 0; q2 < 4; q2++) pk[q2] = f2bf(bf2f(pk[q2]) + bf2f(rv[q2]));
        }
        *(uint2*)&outH[o] = *(uint2*)pk;
      }
    }
  } else {
#pragma unroll
    for (int j = 0; j < 4; j++) {
      const int gn = n0 + wn + j * 16 + l16;
      if (gn < Nstore) {
        const float bv = bias ? bias[gn] : 0.f;
#pragma unroll
        for (int i = 0; i < 4; i++)
#pragma unroll
          for (int r = 0; r < 4; r++) {
            const int gm = m0 + wm + i * 16 + quad * 4 + r;
            outF[(size_t)gm * Nstore + gn] = acc[i][j][r] + bv;
          }
      }
    }
  }
}

// ---------------- fused causal attention (load-balanced, bank-swizzled) ----------------
// Wave w owns Q-tiles {w, 15-w} (16 rows each): causal work = exactly 5 tile-chunks per
// wave (was 2..8 -> barrier-bound at 8). Kc/Vtc/P stored with chunk-XOR swizzle
// (slot = chunk ^ key(row)) -> conflict-free writes AND b128 reads, 16B alignment kept.
__global__ __launch_bounds__(512) void attn_k(const u16* __restrict__ qkv,
                                              u16* __restrict__ att) {
  __shared__ u16 Kc[64 * 64];    // K chunk  [s][d],  slot = (d>>3) ^ (s&7) ^ ((s>>3)&7)
  __shared__ u16 Vtc[64 * 64];   // V^T chunk [d][s], slot = (s>>3) ^ (d&7) ^ ((d>>3)&7)
  __shared__ u16 Pl[8 * 16 * 64];// per-wave P [16][64], slot = ch ^ (row>>2 | (row&1)<<2)
  const int b = blockIdx.x / NH, h = blockIdx.x % NH;
  const int tid = threadIdx.x, lane = tid & 63, w = tid >> 6;
  const int quad = lane >> 4, l16 = lane & 15;
  const int rowb = b * T_SEQ;
  const int tiles[2] = {w, 15 - w};

  // Q fragments (A-layout) from global, resident all kernel
  bf16x8 qf[2][2];
#pragma unroll
  for (int ti = 0; ti < 2; ti++)
#pragma unroll
    for (int kk = 0; kk < 2; kk++)
      qf[ti][kk] = *(const bf16x8*)(qkv + (size_t)(rowb + tiles[ti] * 16 + l16) * QKV_N +
                                    h * 64 + kk * 32 + quad * 8);

  f32x4 Oa[2][4];
  float mrun[2][4], lrun[2][4];
#pragma unroll
  for (int ti = 0; ti < 2; ti++) {
#pragma unroll
    for (int di = 0; di < 4; di++) Oa[ti][di] = (f32x4){0.f, 0.f, 0.f, 0.f};
#pragma unroll
    for (int r = 0; r < 4; r++) { mrun[ti][r] = -1e30f; lrun[ti][r] = 0.f; }
  }

  u16* Pw = &Pl[w * 1024];
  const int sr = tid >> 3, sseg = tid & 7;       // sr: s-row 0..63, sseg: 16B chunk 0..7
  const int kst = sseg ^ (sr & 7) ^ ((sr >> 3) & 7);

  for (int c = 0; c < 4; c++) {
    const int s0 = c * 64;
    __syncthreads();                             // WAR
    // stage K chunk (coalesced uint4, swizzled slot)
    *(uint4*)&Kc[sr * 64 + kst * 8] =
        *(const uint4*)(qkv + (size_t)(rowb + s0 + sr) * QKV_N + 384 + h * 64 + sseg * 8);
    // stage V^T chunk (scalar scatter, swizzled slot -> conflict-free)
    {
      union { uint4 u; u16 us[8]; } tb;
      tb.u = *(const uint4*)(qkv + (size_t)(rowb + s0 + sr) * QKV_N + 768 + h * 64 + sseg * 8);
#pragma unroll
      for (int j = 0; j < 8; j++) {
        int d = sseg * 8 + j;
        int vst = (sr >> 3) ^ (d & 7) ^ ((d >> 3) & 7);
        Vtc[d * 64 + vst * 8 + (sr & 7)] = tb.us[j];
      }
    }
    __syncthreads();                             // RAW

    bf16x8 kf[4][2], vf[4][2];
    bool loaded = false;
#pragma unroll
    for (int ti = 0; ti < 2; ti++) {
      const int t = tiles[ti];
      if (t < 4 * c) continue;                   // causal: tile needs chunks 0..t/4
      if (!loaded) {
        loaded = true;
#pragma unroll
        for (int ni = 0; ni < 4; ni++)
#pragma unroll
          for (int kk = 0; kk < 2; kk++) {
            int srow = ni * 16 + l16;
            int ks = (kk * 4 + quad) ^ (srow & 7) ^ ((srow >> 3) & 7);
            kf[ni][kk] = *(const bf16x8*)&Kc[srow * 64 + ks * 8];
            int drow = ni * 16 + l16;            // same index math for V^T rows
            int vs = (kk * 4 + quad) ^ (drow & 7) ^ ((drow >> 3) & 7);
            vf[ni][kk] = *(const bf16x8*)&Vtc[drow * 64 + vs * 8];
          }
      }
      // S = Q K^T
      f32x4 S[4];
#pragma unroll
      for (int ni = 0; ni < 4; ni++) {
        f32x4 z = (f32x4){0.f, 0.f, 0.f, 0.f};
        z = __builtin_amdgcn_mfma_f32_16x16x32_bf16(qf[ti][0], kf[ni][0], z, 0, 0, 0);
        S[ni] = __builtin_amdgcn_mfma_f32_16x16x32_bf16(qf[ti][1], kf[ni][1], z, 0, 0, 0);
      }
      const bool diag = ((t >> 2) == c);
#pragma unroll
      for (int ni = 0; ni < 4; ni++)
#pragma unroll
        for (int r = 0; r < 4; r++) {
          float xv = S[ni][r] * 0.125f;          // DH^-0.5
          if (diag) {
            int trow = t * 16 + quad * 4 + r;
            int s = s0 + ni * 16 + l16;
            if (s > trow) xv = -1e30f;
          }
          S[ni][r] = xv;
        }
      // online softmax (row in 16 lanes of one quad)
#pragma unroll
      for (int r = 0; r < 4; r++) {
        float mx = fmaxf(fmaxf(S[0][r], S[1][r]), fmaxf(S[2][r], S[3][r]));
        mx = fmaxf(mx, __shfl_xor(mx, 1));
        mx = fmaxf(mx, __shfl_xor(mx, 2));
        mx = fmaxf(mx, __shfl_xor(mx, 4));
        mx = fmaxf(mx, __shfl_xor(mx, 8));
        float mnew = fmaxf(mrun[ti][r], mx);
        float alpha = __expf(mrun[ti][r] - mnew);
        float ls = 0.f;
#pragma unroll
        for (int ni = 0; ni < 4; ni++) {
          float p = __expf(S[ni][r] - mnew);
          S[ni][r] = p; ls += p;
        }
        ls += __shfl_xor(ls, 1); ls += __shfl_xor(ls, 2);
        ls += __shfl_xor(ls, 4); ls += __shfl_xor(ls, 8);
        lrun[ti][r] = lrun[ti][r] * alpha + ls;
        mrun[ti][r] = mnew;
#pragma unroll
        for (int di = 0; di < 4; di++) Oa[ti][di][r] *= alpha;
      }
      // P -> per-wave LDS (C-layout write, swizzle key = row>>2 | (row&1)<<2)
#pragma unroll
      for (int ni = 0; ni < 4; ni++)
#pragma unroll
        for (int r = 0; r < 4; r++) {
          int ch = 2 * ni + (l16 >> 3);
          int st = ch ^ (quad | ((r & 1) << 2));
          Pw[(quad * 4 + r) * 64 + st * 8 + (l16 & 7)] = f2bf(S[ni][r]);
        }
      // A-layout read-back (compiler inserts lgkmcnt wait; wave-private, no barrier)
      bf16x8 pf[2];
#pragma unroll
      for (int kk = 0; kk < 2; kk++) {
        int key = (l16 >> 2) | ((l16 & 1) << 2);
        int st = (kk * 4 + quad) ^ key;
        pf[kk] = *(const bf16x8*)&Pw[l16 * 64 + st * 8];
      }
      // O += P V
#pragma unroll
      for (int di = 0; di < 4; di++) {
        Oa[ti][di] = __builtin_amdgcn_mfma_f32_16x16x32_bf16(pf[0], vf[di][0], Oa[ti][di], 0, 0, 0);
        Oa[ti][di] = __builtin_amdgcn_mfma_f32_16x16x32_bf16(pf[1], vf[di][1], Oa[ti][di], 0, 0, 0);
      }
    }
  }

  // normalize + store
#pragma unroll
  for (int ti = 0; ti < 2; ti++)
#pragma unroll
    for (int r = 0; r < 4; r++) {
      float inv = 1.f / lrun[ti][r];
      int trow = tiles[ti] * 16 + quad * 4 + r;
#pragma unroll
      for (int di = 0; di < 4; di++)
        att[(size_t)(rowb + trow) * E_DIM + h * 64 + di * 16 + l16] = f2bf(Oa[ti][di][r] * inv);
    }
}

// ---------------- loss: grid-stride, 1 atomic per block ----------------
__global__ __launch_bounds__(256) void loss_k(const float* __restrict__ logits,
                                              const int* __restrict__ tgt,
                                              float* __restrict__ loss) {
  __shared__ float part[4];
  const int tid = threadIdx.x, lane = tid & 63, w = tid >> 6;
  const int wave_id = blockIdx.x * 4 + w;          // 512 blocks -> 2048 waves
  float acc = 0.f;
  for (int t = wave_id; t < BT; t += 2048) {
    const float* row = logits + (size_t)t * VOC;
    float a = row[lane];
    float b = (lane == 0) ? row[64] : -1e30f;
    float mx = fmaxf(a, b);
#pragma unroll
    for (int d = 1; d < 64; d <<= 1) mx = fmaxf(mx, __shfl_xor(mx, d));
    float sum = __expf(a - mx) + ((lane == 0) ? __expf(b - mx) : 0.f);
#pragma unroll
    for (int d = 1; d < 64; d <<= 1) sum += __shfl_xor(sum, d);
    if (lane == 0) acc += mx + __logf(sum) - row[tgt[t]];
  }
  if (lane == 0) part[w] = acc;
  __syncthreads();
  if (tid == 0)
    atomicAdd(loss, (part[0] + part[1] + part[2] + part[3]) * (1.f / (float)BT));
}

// ---------------- host ----------------
extern "C" void kernel_launch(void* const* d_in, const int* in_sizes, int n_in,
                              void* d_out, int out_size, void* d_ws, size_t ws_size,
                              hipStream_t stream) {
  (void)in_sizes; (void)n_in; (void)out_size; (void)ws_size;
  const int*   idx  = (const int*)d_in[0];
  const int*   tgt  = (const int*)d_in[1];
  const float* tok  = (const float*)d_in[2];
  const float* pos  = (const float*)d_in[3];
  const float* Wq   = (const float*)d_in[4];
  const float* Wk   = (const float*)d_in[5];
  const float* Wv   = (const float*)d_in[6];
  const float* Wo   = (const float*)d_in[7];
  const float* bo   = (const float*)d_in[8];
  const float* ln1s = (const float*)d_in[9];
  const float* ln1b = (const float*)d_in[10];
  const float* ln2s = (const float*)d_in[11];
  const float* ln2b = (const float*)d_in[12];
  const float* W1   = (const float*)d_in[13];
  const float* b1   = (const float*)d_in[14];
  const float* W2   = (const float*)d_in[15];
  const float* b2   = (const float*)d_in[16];
  const float* lnfs = (const float*)d_in[17];
  const float* lnfb = (const float*)d_in[18];
  const float* Wout = (const float*)d_in[19];
  const float* bout = (const float*)d_in[20];

  char* w = (char*)d_ws;
  u16* x      = (u16*)w;    w += (size_t)BT * E_DIM * 2;      // bf16 residual stream
  u16* hb     = (u16*)w;    w += (size_t)BT * E_DIM * 2;
  u16* attb   = (u16*)w;    w += (size_t)BT * E_DIM * 2;
  u16* big    = (u16*)w;    w += (size_t)BT * FF_DIM * 2;     // qkv / ff union
  u16* Wqkv_t = (u16*)w;    w += (size_t)NL * QKV_N * E_DIM * 2;
  u16* Wo_t   = (u16*)w;    w += (size_t)NL * E_DIM * E_DIM * 2;
  u16* W1_t   = (u16*)w;    w += (size_t)NL * FF_DIM * E_DIM * 2;
  u16* W2_t   = (u16*)w;    w += (size_t)NL * E_DIM * FF_DIM * 2;
  u16* Wout_t = (u16*)w;    w += (size_t)128 * E_DIM * 2;
  u16* qkv = big;
  u16* ff  = big;

  float* logits = (float*)d_out;
  float* loss   = logits + (size_t)BT * VOC;

  hipMemsetAsync(Wout_t, 0, 128 * E_DIM * 2, stream);
  transpose_t<<<dim3(12, 2, 36), 256, 0, stream>>>(Wq, Wqkv_t, 384, 64,
      24576, 442368, 6, 24576, 0);
  transpose_t<<<dim3(12, 2, 36), 256, 0, stream>>>(Wk, Wqkv_t, 384, 64,
      24576, 442368, 6, 24576, (long)384 * 384);
  transpose_t<<<dim3(12, 2, 36), 256, 0, stream>>>(Wv, Wqkv_t, 384, 64,
      24576, 442368, 6, 24576, (long)768 * 384);
  transpose_t<<<dim3(12, 12, 6), 256, 0, stream>>>(Wo, Wo_t, 384, 384,
      147456, 147456, 1, 0, 0);
  transpose_t<<<dim3(12, 48, 6), 256, 0, stream>>>(W1, W1_t, 384, 1536,
      589824, 589824, 1, 0, 0);
  transpose_t<<<dim3(48, 12, 6), 256, 0, stream>>>(W2, W2_t, 1536, 384,
      589824, 589824, 1, 0, 0);
  transpose_t<<<dim3(12, 3, 1), 256, 0, stream>>>(Wout, Wout_t, 384, 65,
      0, 0, 1, 0, 0);

  embed_k<<<6144, 256, 0, stream>>>(idx, tok, pos, x);

  for (int l = 0; l < NL; l++) {
    ln_k<<<8192, 256, 0, stream>>>(x, ln1s + l * E_DIM, ln1b + l * E_DIM, hb);
    gemm_d<<<dim3(256, 9), 256, 0, stream>>>(hb, Wqkv_t + (size_t)l * QKV_N * E_DIM,
                                             384, QKV_N, nullptr, nullptr, qkv, nullptr, 0);
    attn_k<<<768, 512, 0, stream>>>(qkv, attb);
    gemm_d<<<dim3(256, 3), 256, 0, stream>>>(attb, Wo_t + (size_t)l * E_DIM * E_DIM,
                                             384, E_DIM, bo + l * E_DIM, x, x, nullptr, 0);
    ln_k<<<8192, 256, 0, stream>>>(x, ln2s + l * E_DIM, ln2b + l * E_DIM, hb);
    gemm_d<<<dim3(256, 12), 256, 0, stream>>>(hb, W1_t + (size_t)l * FF_DIM * E_DIM,
                                              384, FF_DIM, b1 + l * FF_DIM, nullptr, ff, nullptr, 1);
    gemm_d<<<dim3(256, 3), 256, 0, stream>>>(ff, W2_t + (size_t)l * E_DIM * FF_DIM,
                                             1536, E_DIM, b2 + l * E_DIM, x, x, nullptr, 0);
  }
  ln_k<<<8192, 256, 0, stream>>>(x, lnfs, lnfb, hb);
  gemm_d<<<dim3(256, 1), 256, 0, stream>>>(hb, Wout_t, 384, VOC, bout, nullptr, nullptr, logits, 0);

  hipMemsetAsync(loss, 0, 4, stream);
  loss_k<<<512, 256, 0, stream>>>(logits, tgt, loss);
}

// Round 6
// 1853.212 us; speedup vs baseline: 1.2727x; 1.2727x over previous
//
#include <hip/hip_runtime.h>

// ---- problem constants ----
#define BT      32768     // B*T = 128*256
#define T_SEQ   256
#define E_DIM   384
#define NH      6
#define NL      6
#define VOC     65
#define FF_DIM  1536
#define QKV_N   1152      // 3*E

typedef short bf16x8 __attribute__((ext_vector_type(8)));   // 8 bf16 (4 VGPRs)
typedef float f32x4  __attribute__((ext_vector_type(4)));
typedef unsigned short u16;

typedef const unsigned int __attribute__((address_space(1))) gu32;
typedef unsigned int       __attribute__((address_space(3))) lu32;

__device__ __forceinline__ u16 f2bf(float x) {              // RNE fp32->bf16
  unsigned u = __builtin_bit_cast(unsigned, x);
  u += 0x7fffu + ((u >> 16) & 1u);
  return (u16)(u >> 16);
}
__device__ __forceinline__ float bf2f(u16 v) {
  unsigned u = ((unsigned)v) << 16;
  return __builtin_bit_cast(float, u);
}

__device__ __forceinline__ void load_lds_16(const void* g, void* l) {
  __builtin_amdgcn_global_load_lds((gu32*)g, (lu32*)l, 16, 0, 0);
}

// ---------------- unified LDS-tiled transpose: src[b][R][C] fp32 -> dst bf16 [.. C][R] ----------------
__global__ __launch_bounds__(256) void transpose_t(
    const float* __restrict__ src, u16* __restrict__ dst, int R, int C,
    long sbs, long dbs_outer, int inner, long dbs_inner, long dbase) {
  __shared__ float t[32][33];
  const int b = blockIdx.z;
  const float* s = src + (long)b * sbs;
  u16* d = dst + dbase + (long)(b / inner) * dbs_outer + (long)(b % inner) * dbs_inner;
  const int r0 = blockIdx.x * 32, c0 = blockIdx.y * 32;
  const int tx = threadIdx.x & 31, ty = threadIdx.x >> 5;   // 32 x 8
#pragma unroll
  for (int i = 0; i < 4; i++) {
    int rr = ty + i * 8;
    int r = r0 + rr, c = c0 + tx;
    if (r < R && c < C) t[rr][tx] = s[(long)r * C + c];
  }
  __syncthreads();
#pragma unroll
  for (int i = 0; i < 4; i++) {
    int cc = ty + i * 8;
    int c = c0 + cc, r = r0 + tx;
    if (c < C && r < R) d[(long)c * R + r] = f2bf(t[tx][cc]);
  }
}

// ---------------- embedding (bf16 out) ----------------
__global__ __launch_bounds__(256) void embed_k(const int* __restrict__ idx,
                                               const float* __restrict__ tok,
                                               const float* __restrict__ pos,
                                               u16* __restrict__ x) {
  int i = blockIdx.x * 256 + threadIdx.x;        // over BT*48 groups of 8
  int bt = i / 48, q = i - bt * 48;
  int t = bt & 255;
  const float4* tp = (const float4*)(tok + (size_t)idx[bt] * E_DIM + q * 8);
  const float4* pp = (const float4*)(pos + (size_t)t * E_DIM + q * 8);
  float4 a0 = tp[0], a1 = tp[1], p0 = pp[0], p1 = pp[1];
  u16 o[8];
  o[0] = f2bf(a0.x + p0.x); o[1] = f2bf(a0.y + p0.y);
  o[2] = f2bf(a0.z + p0.z); o[3] = f2bf(a0.w + p0.w);
  o[4] = f2bf(a1.x + p1.x); o[5] = f2bf(a1.y + p1.y);
  o[6] = f2bf(a1.z + p1.z); o[7] = f2bf(a1.w + p1.w);
  *(bf16x8*)(x + (size_t)bt * E_DIM + q * 8) = *(bf16x8*)o;
}

// ---------------- layernorm (bf16 in -> bf16 out, fp32 math) ----------------
__global__ __launch_bounds__(256) void ln_k(const u16* __restrict__ x,
                                            const float* __restrict__ gam,
                                            const float* __restrict__ bet,
                                            u16* __restrict__ out) {
  int tid = threadIdx.x, lane = tid & 63, w = tid >> 6;
  size_t token = (size_t)blockIdx.x * 4 + w;
  const u16* xr = x + token * E_DIM;
  u16 raw[6];
  *(uint2*)raw          = *(const uint2*)(xr + 4 * lane);
  *(unsigned*)(raw + 4) = *(const unsigned*)(xr + 256 + 2 * lane);
  float v[6]; float s = 0.f;
#pragma unroll
  for (int i = 0; i < 6; i++) { v[i] = bf2f(raw[i]); s += v[i]; }
#pragma unroll
  for (int d = 1; d < 64; d <<= 1) s += __shfl_xor(s, d);
  float mean = s * (1.f / E_DIM);
  float q = 0.f;
#pragma unroll
  for (int i = 0; i < 6; i++) { float d0 = v[i] - mean; q += d0 * d0; }
#pragma unroll
  for (int d = 1; d < 64; d <<= 1) q += __shfl_xor(q, d);
  float r = rsqrtf(q * (1.f / E_DIM) + 1e-5f);
  int e[6] = {4 * lane, 4 * lane + 1, 4 * lane + 2, 4 * lane + 3,
              256 + 2 * lane, 256 + 2 * lane + 1};
  u16 o[6];
#pragma unroll
  for (int i = 0; i < 6; i++)
    o[i] = f2bf((v[i] - mean) * r * gam[e[i]] + bet[e[i]]);
  u16* orow = out + token * E_DIM;
  *(uint2*)(orow + 4 * lane)          = *(uint2*)o;
  *(unsigned*)(orow + 256 + 2 * lane) = *(unsigned*)(o + 4);
}

// ---------------- dbuf + swizzled DMA MFMA GEMM (R0-exact): C = A @ Bt^T ------
// 128x128 tile, BK=32, double-buffered DMA staging. 32 KB LDS -> 5 blocks/CU;
// used for the occupancy-sensitive QKV GEMM (grid 2304 = 9 blocks/CU of work).
__global__ __launch_bounds__(256) void gemm_d(
    const u16* __restrict__ A, const u16* __restrict__ Bt, int K, int Nstore,
    const float* __restrict__ bias, const u16* __restrict__ resid,
    u16* __restrict__ outH, float* __restrict__ outF, int relu) {
  __shared__ u16 smem[16384];                 // As[2][128][32] | Bs[2][128][32]
  u16* As = smem;
  u16* Bs = smem + 8192;
  const int tid = threadIdx.x, lane = tid & 63, wv = tid >> 6;
  const int quad = lane >> 4, l16 = lane & 15;
  const int m0 = blockIdx.x * 128, n0 = blockIdx.y * 128;
  const int wm = (wv & 1) * 64, wn = (wv >> 1) * 64;

  const int lrow = lane >> 2;                        // within-group row 0..15
  const int lchunk = (lane & 3) ^ ((lane >> 3) & 3); // swizzled source chunk

  f32x4 acc[4][4];
#pragma unroll
  for (int i = 0; i < 4; i++)
#pragma unroll
    for (int j = 0; j < 4; j++) acc[i][j] = (f32x4){0.f, 0.f, 0.f, 0.f};

  auto stage = [&](int sel, int k0) {
#pragma unroll
    for (int j = 0; j < 2; j++) {
      int rid = wv * 2 + j;                    // 8 groups of 16 rows
      int r = rid * 16 + lrow;
      load_lds_16(A + (size_t)(m0 + r) * K + k0 + lchunk * 8, &As[sel * 4096 + rid * 512]);
      load_lds_16(Bt + (size_t)(n0 + r) * K + k0 + lchunk * 8, &Bs[sel * 4096 + rid * 512]);
    }
  };

  const int NK = K >> 5;
  stage(0, 0);
  __syncthreads();                             // drain prologue DMA
  const int slot = (quad ^ ((l16 >> 1) & 3)) * 8;    // un-swizzle for fragment read
  for (int kt = 0; kt < NK; kt++) {
    const int cur = kt & 1;
    if (kt + 1 < NK) stage(cur ^ 1, (kt + 1) * 32);  // prefetch; drain at loop barrier
    const u16* Ab = As + cur * 4096;
    const u16* Bb = Bs + cur * 4096;
    bf16x8 af[4], bfr[4];
#pragma unroll
    for (int i = 0; i < 4; i++) af[i]  = *(const bf16x8*)&Ab[(wm + i * 16 + l16) * 32 + slot];
#pragma unroll
    for (int j = 0; j < 4; j++) bfr[j] = *(const bf16x8*)&Bb[(wn + j * 16 + l16) * 32 + slot];
#pragma unroll
    for (int i = 0; i < 4; i++)
#pragma unroll
      for (int j = 0; j < 4; j++)
        acc[i][j] = __builtin_amdgcn_mfma_f32_16x16x32_bf16(af[i], bfr[j], acc[i][j], 0, 0, 0);
    __syncthreads();   // drains prefetch (after compute overlap) + guards dbuf reuse
  }

  if (outH) {
#pragma unroll
    for (int p = 0; p < 4; p++) {
      if (p) __syncthreads();
      if ((wv >> 1) == (p >> 1)) {
#pragma unroll
        for (int jj = 0; jj < 2; jj++) {
          int j = (p & 1) * 2 + jj;
          int gn = n0 + wn + j * 16 + l16;
          float bv = bias ? bias[gn] : 0.f;
          int lcol = jj * 16 + l16;
#pragma unroll
          for (int i = 0; i < 4; i++)
#pragma unroll
            for (int r = 0; r < 4; r++) {
              float v = acc[i][j][r] + bv;
              if (relu) v = fmaxf(v, 0.f);
              smem[(wm + i * 16 + quad * 4 + r) * 36 + lcol] = f2bf(v);
            }
        }
      }
      __syncthreads();
      const int gc0 = n0 + p * 32;
#pragma unroll
      for (int s = 0; s < 4; s++) {
        int row = s * 32 + (tid >> 3);
        int seg = (tid & 7) * 4;
        u16 pk[4];
        *(uint2*)pk = *(const uint2*)&smem[row * 36 + seg];
        size_t o = (size_t)(m0 + row) * Nstore + gc0 + seg;
        if (resid) {
          u16 rv[4];
          *(uint2*)rv = *(const uint2*)&resid[o];
#pragma unroll
          for (int q2 = 0; q2 < 4; q2++) pk[q2] = f2bf(bf2f(pk[q2]) + bf2f(rv[q2]));
        }
        *(uint2*)&outH[o] = *(uint2*)pk;
      }
    }
  } else {
#pragma unroll
    for (int j = 0; j < 4; j++) {
      const int gn = n0 + wn + j * 16 + l16;
      if (gn < Nstore) {
        const float bv = bias ? bias[gn] : 0.f;
#pragma unroll
        for (int i = 0; i < 4; i++)
#pragma unroll
          for (int r = 0; r < 4; r++) {
            const int gm = m0 + wm + i * 16 + quad * 4 + r;
            outF[(size_t)gm * Nstore + gn] = acc[i][j][r] + bv;
          }
      }
    }
  }
}

// ---------------- triple-buffered counted-vmcnt MFMA GEMM (R4-exact) ----------------
// Same structure as gemm_d but 3-buffer A/B staging: stage k+2 ahead, end-of-step
// `s_waitcnt vmcnt(4)` retires the next step's buffer (issued ~2 steps ago) while
// the newest 4 loads stay in flight; raw s_barrier (no full drain mid-loop).
// 48 KB LDS -> 3 blocks/CU: deployed ONLY where residency is grid-limited to <=3
// anyway (FF1 measured 72.1 vs 76.4 µs; FF2/Wo grid=768; logits grid=256).
__global__ __launch_bounds__(256) void gemm_p(
    const u16* __restrict__ A, const u16* __restrict__ Bt, int K, int Nstore,
    const float* __restrict__ bias, const u16* __restrict__ resid,
    u16* __restrict__ outH, float* __restrict__ outF, int relu) {
  __shared__ u16 smem[24576];                 // As[3][128][32] | Bs[3][128][32]
  u16* As = smem;
  u16* Bs = smem + 12288;
  const int tid = threadIdx.x, lane = tid & 63, wv = tid >> 6;
  const int quad = lane >> 4, l16 = lane & 15;
  const int m0 = blockIdx.x * 128, n0 = blockIdx.y * 128;
  const int wm = (wv & 1) * 64, wn = (wv >> 1) * 64;

  const int lrow = lane >> 2;                        // within-group row 0..15
  const int lchunk = (lane & 3) ^ ((lane >> 3) & 3); // swizzled source chunk

  f32x4 acc[4][4];
#pragma unroll
  for (int i = 0; i < 4; i++)
#pragma unroll
    for (int j = 0; j < 4; j++) acc[i][j] = (f32x4){0.f, 0.f, 0.f, 0.f};

  auto stage = [&](int sel, int k0) {                // 4 VMEM ops per call
#pragma unroll
    for (int j = 0; j < 2; j++) {
      int rid = wv * 2 + j;                    // 8 groups of 16 rows
      int r = rid * 16 + lrow;
      load_lds_16(A + (size_t)(m0 + r) * K + k0 + lchunk * 8, &As[sel * 4096 + rid * 512]);
      load_lds_16(Bt + (size_t)(n0 + r) * K + k0 + lchunk * 8, &Bs[sel * 4096 + rid * 512]);
    }
  };

  const int NK = K >> 5;                       // >= 12 at every call site
  stage(0, 0);
  stage(1, 32);
  asm volatile("s_waitcnt vmcnt(4)" ::: "memory");   // buf0 ready, buf1 in flight
  __builtin_amdgcn_s_barrier();

  const int slot = (quad ^ ((l16 >> 1) & 3)) * 8;    // un-swizzle for fragment read
  int cur = 0, stg = 2;
  for (int kt = 0; kt < NK; kt++) {
    const bool pf = (kt + 2 < NK);
    if (pf) {
      stage(stg, (kt + 2) * 32);
      if (++stg == 3) stg = 0;
    }
    const u16* Ab = As + cur * 4096;
    const u16* Bb = Bs + cur * 4096;
    bf16x8 af[4], bfr[4];
#pragma unroll
    for (int i = 0; i < 4; i++) af[i]  = *(const bf16x8*)&Ab[(wm + i * 16 + l16) * 32 + slot];
#pragma unroll
    for (int j = 0; j < 4; j++) bfr[j] = *(const bf16x8*)&Bb[(wn + j * 16 + l16) * 32 + slot];
#pragma unroll
    for (int i = 0; i < 4; i++)
#pragma unroll
      for (int j = 0; j < 4; j++)
        acc[i][j] = __builtin_amdgcn_mfma_f32_16x16x32_bf16(af[i], bfr[j], acc[i][j], 0, 0, 0);
    if (pf) asm volatile("s_waitcnt vmcnt(4)" ::: "memory");  // retire buf kt+1's loads
    else    asm volatile("s_waitcnt vmcnt(0)" ::: "memory");  // tail: drain remainder
    __builtin_amdgcn_s_barrier();
    if (++cur == 3) cur = 0;
  }

  if (outH) {
#pragma unroll
    for (int p = 0; p < 4; p++) {
      if (p) __syncthreads();
      if ((wv >> 1) == (p >> 1)) {
#pragma unroll
        for (int jj = 0; jj < 2; jj++) {
          int j = (p & 1) * 2 + jj;
          int gn = n0 + wn + j * 16 + l16;
          float bv = bias ? bias[gn] : 0.f;
          int lcol = jj * 16 + l16;
#pragma unroll
          for (int i = 0; i < 4; i++)
#pragma unroll
            for (int r = 0; r < 4; r++) {
              float v = acc[i][j][r] + bv;
              if (relu) v = fmaxf(v, 0.f);
              smem[(wm + i * 16 + quad * 4 + r) * 36 + lcol] = f2bf(v);
            }
        }
      }
      __syncthreads();
      const int gc0 = n0 + p * 32;
#pragma unroll
      for (int s = 0; s < 4; s++) {
        int row = s * 32 + (tid >> 3);
        int seg = (tid & 7) * 4;
        u16 pk[4];
        *(uint2*)pk = *(const uint2*)&smem[row * 36 + seg];
        size_t o = (size_t)(m0 + row) * Nstore + gc0 + seg;
        if (resid) {
          u16 rv[4];
          *(uint2*)rv = *(const uint2*)&resid[o];
#pragma unroll
          for (int q2 = 0; q2 < 4; q2++) pk[q2] = f2bf(bf2f(pk[q2]) + bf2f(rv[q2]));
        }
        *(uint2*)&outH[o] = *(uint2*)pk;
      }
    }
  } else {
#pragma unroll
    for (int j = 0; j < 4; j++) {
      const int gn = n0 + wn + j * 16 + l16;
      if (gn < Nstore) {
        const float bv = bias ? bias[gn] : 0.f;
#pragma unroll
        for (int i = 0; i < 4; i++)
#pragma unroll
          for (int r = 0; r < 4; r++) {
            const int gm = m0 + wm + i * 16 + quad * 4 + r;
            outF[(size_t)gm * Nstore + gn] = acc[i][j][r] + bv;
          }
      }
    }
  }
}

// ---------------- fused causal attention (load-balanced, bank-swizzled) ----------------
// Wave w owns Q-tiles {w, 15-w} (16 rows each): causal work = exactly 5 tile-chunks per
// wave (was 2..8 -> barrier-bound at 8). Kc/Vtc/P stored with chunk-XOR swizzle
// (slot = chunk ^ key(row)) -> conflict-free writes AND b128 reads, 16B alignment kept.
__global__ __launch_bounds__(512) void attn_k(const u16* __restrict__ qkv,
                                              u16* __restrict__ att) {
  __shared__ u16 Kc[64 * 64];    // K chunk  [s][d],  slot = (d>>3) ^ (s&7) ^ ((s>>3)&7)
  __shared__ u16 Vtc[64 * 64];   // V^T chunk [d][s], slot = (s>>3) ^ (d&7) ^ ((d>>3)&7)
  __shared__ u16 Pl[8 * 16 * 64];// per-wave P [16][64], slot = ch ^ (row>>2 | (row&1)<<2)
  const int b = blockIdx.x / NH, h = blockIdx.x % NH;
  const int tid = threadIdx.x, lane = tid & 63, w = tid >> 6;
  const int quad = lane >> 4, l16 = lane & 15;
  const int rowb = b * T_SEQ;
  const int tiles[2] = {w, 15 - w};

  // Q fragments (A-layout) from global, resident all kernel
  bf16x8 qf[2][2];
#pragma unroll
  for (int ti = 0; ti < 2; ti++)
#pragma unroll
    for (int kk = 0; kk < 2; kk++)
      qf[ti][kk] = *(const bf16x8*)(qkv + (size_t)(rowb + tiles[ti] * 16 + l16) * QKV_N +
                                    h * 64 + kk * 32 + quad * 8);

  f32x4 Oa[2][4];
  float mrun[2][4], lrun[2][4];
#pragma unroll
  for (int ti = 0; ti < 2; ti++) {
#pragma unroll
    for (int di = 0; di < 4; di++) Oa[ti][di] = (f32x4){0.f, 0.f, 0.f, 0.f};
#pragma unroll
    for (int r = 0; r < 4; r++) { mrun[ti][r] = -1e30f; lrun[ti][r] = 0.f; }
  }

  u16* Pw = &Pl[w * 1024];
  const int sr = tid >> 3, sseg = tid & 7;       // sr: s-row 0..63, sseg: 16B chunk 0..7
  const int kst = sseg ^ (sr & 7) ^ ((sr >> 3) & 7);

  for (int c = 0; c < 4; c++) {
    const int s0 = c * 64;
    __syncthreads();                             // WAR
    // stage K chunk (coalesced uint4, swizzled slot)
    *(uint4*)&Kc[sr * 64 + kst * 8] =
        *(const uint4*)(qkv + (size_t)(rowb + s0 + sr) * QKV_N + 384 + h * 64 + sseg * 8);
    // stage V^T chunk (scalar scatter, swizzled slot -> conflict-free)
    {
      union { uint4 u; u16 us[8]; } tb;
      tb.u = *(const uint4*)(qkv + (size_t)(rowb + s0 + sr) * QKV_N + 768 + h * 64 + sseg * 8);
#pragma unroll
      for (int j = 0; j < 8; j++) {
        int d = sseg * 8 + j;
        int vst = (sr >> 3) ^ (d & 7) ^ ((d >> 3) & 7);
        Vtc[d * 64 + vst * 8 + (sr & 7)] = tb.us[j];
      }
    }
    __syncthreads();                             // RAW

    bf16x8 kf[4][2], vf[4][2];
    bool loaded = false;
#pragma unroll
    for (int ti = 0; ti < 2; ti++) {
      const int t = tiles[ti];
      if (t < 4 * c) continue;                   // causal: tile needs chunks 0..t/4
      if (!loaded) {
        loaded = true;
#pragma unroll
        for (int ni = 0; ni < 4; ni++)
#pragma unroll
          for (int kk = 0; kk < 2; kk++) {
            int srow = ni * 16 + l16;
            int ks = (kk * 4 + quad) ^ (srow & 7) ^ ((srow >> 3) & 7);
            kf[ni][kk] = *(const bf16x8*)&Kc[srow * 64 + ks * 8];
            int drow = ni * 16 + l16;            // same index math for V^T rows
            int vs = (kk * 4 + quad) ^ (drow & 7) ^ ((drow >> 3) & 7);
            vf[ni][kk] = *(const bf16x8*)&Vtc[drow * 64 + vs * 8];
          }
      }
      // S = Q K^T
      f32x4 S[4];
#pragma unroll
      for (int ni = 0; ni < 4; ni++) {
        f32x4 z = (f32x4){0.f, 0.f, 0.f, 0.f};
        z = __builtin_amdgcn_mfma_f32_16x16x32_bf16(qf[ti][0], kf[ni][0], z, 0, 0, 0);
        S[ni] = __builtin_amdgcn_mfma_f32_16x16x32_bf16(qf[ti][1], kf[ni][1], z, 0, 0, 0);
      }
      const bool diag = ((t >> 2) == c);
#pragma unroll
      for (int ni = 0; ni < 4; ni++)
#pragma unroll
        for (int r = 0; r < 4; r++) {
          float xv = S[ni][r] * 0.125f;          // DH^-0.5
          if (diag) {
            int trow = t * 16 + quad * 4 + r;
            int s = s0 + ni * 16 + l16;
            if (s > trow) xv = -1e30f;
          }
          S[ni][r] = xv;
        }
      // online softmax (row in 16 lanes of one quad)
#pragma unroll
      for (int r = 0; r < 4; r++) {
        float mx = fmaxf(fmaxf(S[0][r], S[1][r]), fmaxf(S[2][r], S[3][r]));
        mx = fmaxf(mx, __shfl_xor(mx, 1));
        mx = fmaxf(mx, __shfl_xor(mx, 2));
        mx = fmaxf(mx, __shfl_xor(mx, 4));
        mx = fmaxf(mx, __shfl_xor(mx, 8));
        float mnew = fmaxf(mrun[ti][r], mx);
        float alpha = __expf(mrun[ti][r] - mnew);
        float ls = 0.f;
#pragma unroll
        for (int ni = 0; ni < 4; ni++) {
          float p = __expf(S[ni][r] - mnew);
          S[ni][r] = p; ls += p;
        }
        ls += __shfl_xor(ls, 1); ls += __shfl_xor(ls, 2);
        ls += __shfl_xor(ls, 4); ls += __shfl_xor(ls, 8);
        lrun[ti][r] = lrun[ti][r] * alpha + ls;
        mrun[ti][r] = mnew;
#pragma unroll
        for (int di = 0; di < 4; di++) Oa[ti][di][r] *= alpha;
      }
      // P -> per-wave LDS (C-layout write, swizzle key = row>>2 | (row&1)<<2)
#pragma unroll
      for (int ni = 0; ni < 4; ni++)
#pragma unroll
        for (int r = 0; r < 4; r++) {
          int ch = 2 * ni + (l16 >> 3);
          int st = ch ^ (quad | ((r & 1) << 2));
          Pw[(quad * 4 + r) * 64 + st * 8 + (l16 & 7)] = f2bf(S[ni][r]);
        }
      // A-layout read-back (compiler inserts lgkmcnt wait; wave-private, no barrier)
      bf16x8 pf[2];
#pragma unroll
      for (int kk = 0; kk < 2; kk++) {
        int key = (l16 >> 2) | ((l16 & 1) << 2);
        int st = (kk * 4 + quad) ^ key;
        pf[kk] = *(const bf16x8*)&Pw[l16 * 64 + st * 8];
      }
      // O += P V
#pragma unroll
      for (int di = 0; di < 4; di++) {
        Oa[ti][di] = __builtin_amdgcn_mfma_f32_16x16x32_bf16(pf[0], vf[di][0], Oa[ti][di], 0, 0, 0);
        Oa[ti][di] = __builtin_amdgcn_mfma_f32_16x16x32_bf16(pf[1], vf[di][1], Oa[ti][di], 0, 0, 0);
      }
    }
  }

  // normalize + store
#pragma unroll
  for (int ti = 0; ti < 2; ti++)
#pragma unroll
    for (int r = 0; r < 4; r++) {
      float inv = 1.f / lrun[ti][r];
      int trow = tiles[ti] * 16 + quad * 4 + r;
#pragma unroll
      for (int di = 0; di < 4; di++)
        att[(size_t)(rowb + trow) * E_DIM + h * 64 + di * 16 + l16] = f2bf(Oa[ti][di][r] * inv);
    }
}

// ---------------- loss: grid-stride, 1 atomic per block ----------------
__global__ __launch_bounds__(256) void loss_k(const float* __restrict__ logits,
                                              const int* __restrict__ tgt,
                                              float* __restrict__ loss) {
  __shared__ float part[4];
  const int tid = threadIdx.x, lane = tid & 63, w = tid >> 6;
  const int wave_id = blockIdx.x * 4 + w;          // 512 blocks -> 2048 waves
  float acc = 0.f;
  for (int t = wave_id; t < BT; t += 2048) {
    const float* row = logits + (size_t)t * VOC;
    float a = row[lane];
    float b = (lane == 0) ? row[64] : -1e30f;
    float mx = fmaxf(a, b);
#pragma unroll
    for (int d = 1; d < 64; d <<= 1) mx = fmaxf(mx, __shfl_xor(mx, d));
    float sum = __expf(a - mx) + ((lane == 0) ? __expf(b - mx) : 0.f);
#pragma unroll
    for (int d = 1; d < 64; d <<= 1) sum += __shfl_xor(sum, d);
    if (lane == 0) acc += mx + __logf(sum) - row[tgt[t]];
  }
  if (lane == 0) part[w] = acc;
  __syncthreads();
  if (tid == 0)
    atomicAdd(loss, (part[0] + part[1] + part[2] + part[3]) * (1.f / (float)BT));
}

// ---------------- host ----------------
extern "C" void kernel_launch(void* const* d_in, const int* in_sizes, int n_in,
                              void* d_out, int out_size, void* d_ws, size_t ws_size,
                              hipStream_t stream) {
  (void)in_sizes; (void)n_in; (void)out_size; (void)ws_size;
  const int*   idx  = (const int*)d_in[0];
  const int*   tgt  = (const int*)d_in[1];
  const float* tok  = (const float*)d_in[2];
  const float* pos  = (const float*)d_in[3];
  const float* Wq   = (const float*)d_in[4];
  const float* Wk   = (const float*)d_in[5];
  const float* Wv   = (const float*)d_in[6];
  const float* Wo   = (const float*)d_in[7];
  const float* bo   = (const float*)d_in[8];
  const float* ln1s = (const float*)d_in[9];
  const float* ln1b = (const float*)d_in[10];
  const float* ln2s = (const float*)d_in[11];
  const float* ln2b = (const float*)d_in[12];
  const float* W1   = (const float*)d_in[13];
  const float* b1   = (const float*)d_in[14];
  const float* W2   = (const float*)d_in[15];
  const float* b2   = (const float*)d_in[16];
  const float* lnfs = (const float*)d_in[17];
  const float* lnfb = (const float*)d_in[18];
  const float* Wout = (const float*)d_in[19];
  const float* bout = (const float*)d_in[20];

  char* w = (char*)d_ws;
  u16* x      = (u16*)w;    w += (size_t)BT * E_DIM * 2;      // bf16 residual stream
  u16* hb     = (u16*)w;    w += (size_t)BT * E_DIM * 2;
  u16* attb   = (u16*)w;    w += (size_t)BT * E_DIM * 2;
  u16* big    = (u16*)w;    w += (size_t)BT * FF_DIM * 2;     // qkv / ff union
  u16* Wqkv_t = (u16*)w;    w += (size_t)NL * QKV_N * E_DIM * 2;
  u16* Wo_t   = (u16*)w;    w += (size_t)NL * E_DIM * E_DIM * 2;
  u16* W1_t   = (u16*)w;    w += (size_t)NL * FF_DIM * E_DIM * 2;
  u16* W2_t   = (u16*)w;    w += (size_t)NL * E_DIM * FF_DIM * 2;
  u16* Wout_t = (u16*)w;    w += (size_t)128 * E_DIM * 2;
  u16* qkv = big;
  u16* ff  = big;

  float* logits = (float*)d_out;
  float* loss   = logits + (size_t)BT * VOC;

  hipMemsetAsync(Wout_t, 0, 128 * E_DIM * 2, stream);
  transpose_t<<<dim3(12, 2, 36), 256, 0, stream>>>(Wq, Wqkv_t, 384, 64,
      24576, 442368, 6, 24576, 0);
  transpose_t<<<dim3(12, 2, 36), 256, 0, stream>>>(Wk, Wqkv_t, 384, 64,
      24576, 442368, 6, 24576, (long)384 * 384);
  transpose_t<<<dim3(12, 2, 36), 256, 0, stream>>>(Wv, Wqkv_t, 384, 64,
      24576, 442368, 6, 24576, (long)768 * 384);
  transpose_t<<<dim3(12, 12, 6), 256, 0, stream>>>(Wo, Wo_t, 384, 384,
      147456, 147456, 1, 0, 0);
  transpose_t<<<dim3(12, 48, 6), 256, 0, stream>>>(W1, W1_t, 384, 1536,
      589824, 589824, 1, 0, 0);
  transpose_t<<<dim3(48, 12, 6), 256, 0, stream>>>(W2, W2_t, 1536, 384,
      589824, 589824, 1, 0, 0);
  transpose_t<<<dim3(12, 3, 1), 256, 0, stream>>>(Wout, Wout_t, 384, 65,
      0, 0, 1, 0, 0);

  embed_k<<<6144, 256, 0, stream>>>(idx, tok, pos, x);

  for (int l = 0; l < NL; l++) {
    ln_k<<<8192, 256, 0, stream>>>(x, ln1s + l * E_DIM, ln1b + l * E_DIM, hb);
    gemm_d<<<dim3(256, 9), 256, 0, stream>>>(hb, Wqkv_t + (size_t)l * QKV_N * E_DIM,
                                             384, QKV_N, nullptr, nullptr, qkv, nullptr, 0);
    attn_k<<<768, 512, 0, stream>>>(qkv, attb);
    gemm_p<<<dim3(256, 3), 256, 0, stream>>>(attb, Wo_t + (size_t)l * E_DIM * E_DIM,
                                             384, E_DIM, bo + l * E_DIM, x, x, nullptr, 0);
    ln_k<<<8192, 256, 0, stream>>>(x, ln2s + l * E_DIM, ln2b + l * E_DIM, hb);
    gemm_p<<<dim3(256, 12), 256, 0, stream>>>(hb, W1_t + (size_t)l * FF_DIM * E_DIM,
                                              384, FF_DIM, b1 + l * FF_DIM, nullptr, ff, nullptr, 1);
    gemm_p<<<dim3(256, 3), 256, 0, stream>>>(ff, W2_t + (size_t)l * E_DIM * FF_DIM,
                                             1536, E_DIM, b2 + l * E_DIM, x, x, nullptr, 0);
  }
  ln_k<<<8192, 256, 0, stream>>>(x, lnfs, lnfb, hb);
  gemm_p<<<dim3(256, 1), 256, 0, stream>>>(hb, Wout_t, 384, VOC, bout, nullptr, nullptr, logits, 0);

  hipMemsetAsync(loss, 0, 4, stream);
  loss_k<<<512, 256, 0, stream>>>(logits, tgt, loss);
}

// Round 7
// 1750.217 us; speedup vs baseline: 1.3476x; 1.0588x over previous
//
#include <hip/hip_runtime.h>

// ---- problem constants ----
#define BT      32768     // B*T = 128*256
#define T_SEQ   256
#define E_DIM   384
#define NH      6
#define NL      6
#define VOC     65
#define FF_DIM  1536
#define QKV_N   1152      // 3*E

typedef short bf16x8 __attribute__((ext_vector_type(8)));   // 8 bf16 (4 VGPRs)
typedef float f32x4  __attribute__((ext_vector_type(4)));
typedef unsigned short u16;

typedef const unsigned int __attribute__((address_space(1))) gu32;
typedef unsigned int       __attribute__((address_space(3))) lu32;

__device__ __forceinline__ u16 f2bf(float x) {              // RNE fp32->bf16
  unsigned u = __builtin_bit_cast(unsigned, x);
  u += 0x7fffu + ((u >> 16) & 1u);
  return (u16)(u >> 16);
}
__device__ __forceinline__ float bf2f(u16 v) {
  unsigned u = ((unsigned)v) << 16;
  return __builtin_bit_cast(float, u);
}

__device__ __forceinline__ void load_lds_16(const void* g, void* l) {
  __builtin_amdgcn_global_load_lds((gu32*)g, (lu32*)l, 16, 0, 0);
}

// ---------------- unified LDS-tiled transpose: src[b][R][C] fp32 -> dst bf16 [.. C][R] ----------------
__global__ __launch_bounds__(256) void transpose_t(
    const float* __restrict__ src, u16* __restrict__ dst, int R, int C,
    long sbs, long dbs_outer, int inner, long dbs_inner, long dbase) {
  __shared__ float t[32][33];
  const int b = blockIdx.z;
  const float* s = src + (long)b * sbs;
  u16* d = dst + dbase + (long)(b / inner) * dbs_outer + (long)(b % inner) * dbs_inner;
  const int r0 = blockIdx.x * 32, c0 = blockIdx.y * 32;
  const int tx = threadIdx.x & 31, ty = threadIdx.x >> 5;   // 32 x 8
#pragma unroll
  for (int i = 0; i < 4; i++) {
    int rr = ty + i * 8;
    int r = r0 + rr, c = c0 + tx;
    if (r < R && c < C) t[rr][tx] = s[(long)r * C + c];
  }
  __syncthreads();
#pragma unroll
  for (int i = 0; i < 4; i++) {
    int cc = ty + i * 8;
    int c = c0 + cc, r = r0 + tx;
    if (c < C && r < R) d[(long)c * R + r] = f2bf(t[tx][cc]);
  }
}

// ---------------- embedding (bf16 out) ----------------
__global__ __launch_bounds__(256) void embed_k(const int* __restrict__ idx,
                                               const float* __restrict__ tok,
                                               const float* __restrict__ pos,
                                               u16* __restrict__ x) {
  int i = blockIdx.x * 256 + threadIdx.x;        // over BT*48 groups of 8
  int bt = i / 48, q = i - bt * 48;
  int t = bt & 255;
  const float4* tp = (const float4*)(tok + (size_t)idx[bt] * E_DIM + q * 8);
  const float4* pp = (const float4*)(pos + (size_t)t * E_DIM + q * 8);
  float4 a0 = tp[0], a1 = tp[1], p0 = pp[0], p1 = pp[1];
  u16 o[8];
  o[0] = f2bf(a0.x + p0.x); o[1] = f2bf(a0.y + p0.y);
  o[2] = f2bf(a0.z + p0.z); o[3] = f2bf(a0.w + p0.w);
  o[4] = f2bf(a1.x + p1.x); o[5] = f2bf(a1.y + p1.y);
  o[6] = f2bf(a1.z + p1.z); o[7] = f2bf(a1.w + p1.w);
  *(bf16x8*)(x + (size_t)bt * E_DIM + q * 8) = *(bf16x8*)o;
}

// ---------------- layernorm (bf16 in -> bf16 out, fp32 math) ----------------
__global__ __launch_bounds__(256) void ln_k(const u16* __restrict__ x,
                                            const float* __restrict__ gam,
                                            const float* __restrict__ bet,
                                            u16* __restrict__ out) {
  int tid = threadIdx.x, lane = tid & 63, w = tid >> 6;
  size_t token = (size_t)blockIdx.x * 4 + w;
  const u16* xr = x + token * E_DIM;
  u16 raw[6];
  *(uint2*)raw          = *(const uint2*)(xr + 4 * lane);
  *(unsigned*)(raw + 4) = *(const unsigned*)(xr + 256 + 2 * lane);
  float v[6]; float s = 0.f;
#pragma unroll
  for (int i = 0; i < 6; i++) { v[i] = bf2f(raw[i]); s += v[i]; }
#pragma unroll
  for (int d = 1; d < 64; d <<= 1) s += __shfl_xor(s, d);
  float mean = s * (1.f / E_DIM);
  float q = 0.f;
#pragma unroll
  for (int i = 0; i < 6; i++) { float d0 = v[i] - mean; q += d0 * d0; }
#pragma unroll
  for (int d = 1; d < 64; d <<= 1) q += __shfl_xor(q, d);
  float r = rsqrtf(q * (1.f / E_DIM) + 1e-5f);
  int e[6] = {4 * lane, 4 * lane + 1, 4 * lane + 2, 4 * lane + 3,
              256 + 2 * lane, 256 + 2 * lane + 1};
  u16 o[6];
#pragma unroll
  for (int i = 0; i < 6; i++)
    o[i] = f2bf((v[i] - mean) * r * gam[e[i]] + bet[e[i]]);
  u16* orow = out + token * E_DIM;
  *(uint2*)(orow + 4 * lane)          = *(uint2*)o;
  *(unsigned*)(orow + 256 + 2 * lane) = *(unsigned*)(o + 4);
}

// ---------------- dbuf + swizzled DMA MFMA GEMM (R0-exact): C = A @ Bt^T ------
// 128x128 tile, BK=32, double-buffered DMA staging. 32 KB LDS -> 5 blocks/CU.
// Used for Wo, FF2 (NK=48: counted-vmcnt variant showed a pathological slow
// dispatch in R4's profile -> keep the proven drain-per-step loop here), logits.
__global__ __launch_bounds__(256) void gemm_d(
    const u16* __restrict__ A, const u16* __restrict__ Bt, int K, int Nstore,
    const float* __restrict__ bias, const u16* __restrict__ resid,
    u16* __restrict__ outH, float* __restrict__ outF, int relu) {
  __shared__ u16 smem[16384];                 // As[2][128][32] | Bs[2][128][32]
  u16* As = smem;
  u16* Bs = smem + 8192;
  const int tid = threadIdx.x, lane = tid & 63, wv = tid >> 6;
  const int quad = lane >> 4, l16 = lane & 15;
  const int m0 = blockIdx.x * 128, n0 = blockIdx.y * 128;
  const int wm = (wv & 1) * 64, wn = (wv >> 1) * 64;

  const int lrow = lane >> 2;                        // within-group row 0..15
  const int lchunk = (lane & 3) ^ ((lane >> 3) & 3); // swizzled source chunk

  f32x4 acc[4][4];
#pragma unroll
  for (int i = 0; i < 4; i++)
#pragma unroll
    for (int j = 0; j < 4; j++) acc[i][j] = (f32x4){0.f, 0.f, 0.f, 0.f};

  auto stage = [&](int sel, int k0) {
#pragma unroll
    for (int j = 0; j < 2; j++) {
      int rid = wv * 2 + j;                    // 8 groups of 16 rows
      int r = rid * 16 + lrow;
      load_lds_16(A + (size_t)(m0 + r) * K + k0 + lchunk * 8, &As[sel * 4096 + rid * 512]);
      load_lds_16(Bt + (size_t)(n0 + r) * K + k0 + lchunk * 8, &Bs[sel * 4096 + rid * 512]);
    }
  };

  const int NK = K >> 5;
  stage(0, 0);
  __syncthreads();                             // drain prologue DMA
  const int slot = (quad ^ ((l16 >> 1) & 3)) * 8;    // un-swizzle for fragment read
  for (int kt = 0; kt < NK; kt++) {
    const int cur = kt & 1;
    if (kt + 1 < NK) stage(cur ^ 1, (kt + 1) * 32);  // prefetch; drain at loop barrier
    const u16* Ab = As + cur * 4096;
    const u16* Bb = Bs + cur * 4096;
    bf16x8 af[4], bfr[4];
#pragma unroll
    for (int i = 0; i < 4; i++) af[i]  = *(const bf16x8*)&Ab[(wm + i * 16 + l16) * 32 + slot];
#pragma unroll
    for (int j = 0; j < 4; j++) bfr[j] = *(const bf16x8*)&Bb[(wn + j * 16 + l16) * 32 + slot];
#pragma unroll
    for (int i = 0; i < 4; i++)
#pragma unroll
      for (int j = 0; j < 4; j++)
        acc[i][j] = __builtin_amdgcn_mfma_f32_16x16x32_bf16(af[i], bfr[j], acc[i][j], 0, 0, 0);
    __syncthreads();   // drains prefetch (after compute overlap) + guards dbuf reuse
  }

  if (outH) {
#pragma unroll
    for (int p = 0; p < 4; p++) {
      if (p) __syncthreads();
      if ((wv >> 1) == (p >> 1)) {
#pragma unroll
        for (int jj = 0; jj < 2; jj++) {
          int j = (p & 1) * 2 + jj;
          int gn = n0 + wn + j * 16 + l16;
          float bv = bias ? bias[gn] : 0.f;
          int lcol = jj * 16 + l16;
#pragma unroll
          for (int i = 0; i < 4; i++)
#pragma unroll
            for (int r = 0; r < 4; r++) {
              float v = acc[i][j][r] + bv;
              if (relu) v = fmaxf(v, 0.f);
              smem[(wm + i * 16 + quad * 4 + r) * 36 + lcol] = f2bf(v);
            }
        }
      }
      __syncthreads();
      const int gc0 = n0 + p * 32;
#pragma unroll
      for (int s = 0; s < 4; s++) {
        int row = s * 32 + (tid >> 3);
        int seg = (tid & 7) * 4;
        u16 pk[4];
        *(uint2*)pk = *(const uint2*)&smem[row * 36 + seg];
        size_t o = (size_t)(m0 + row) * Nstore + gc0 + seg;
        if (resid) {
          u16 rv[4];
          *(uint2*)rv = *(const uint2*)&resid[o];
#pragma unroll
          for (int q2 = 0; q2 < 4; q2++) pk[q2] = f2bf(bf2f(pk[q2]) + bf2f(rv[q2]));
        }
        *(uint2*)&outH[o] = *(uint2*)pk;
      }
    }
  } else {
#pragma unroll
    for (int j = 0; j < 4; j++) {
      const int gn = n0 + wn + j * 16 + l16;
      if (gn < Nstore) {
        const float bv = bias ? bias[gn] : 0.f;
#pragma unroll
        for (int i = 0; i < 4; i++)
#pragma unroll
          for (int r = 0; r < 4; r++) {
            const int gm = m0 + wm + i * 16 + quad * 4 + r;
            outF[(size_t)gm * Nstore + gn] = acc[i][j][r] + bv;
          }
      }
    }
  }
}

// ---------------- triple-buffered counted-vmcnt MFMA GEMM (R4-exact) ----------------
// Stage k+2 ahead; end-of-step `s_waitcnt vmcnt(4)` retires the next step's buffer
// (issued ~2 steps ago) while the newest 4 loads stay in flight; raw s_barrier.
// 48 KB LDS -> 3 blocks/CU. Deployed for K=384/NK=12 M-parallel GEMMs where the
// win is reproduced (FF1: 76.4 -> 72.1/72.7 µs across R4/R6) and QKV.
__global__ __launch_bounds__(256) void gemm_p(
    const u16* __restrict__ A, const u16* __restrict__ Bt, int K, int Nstore,
    const float* __restrict__ bias, const u16* __restrict__ resid,
    u16* __restrict__ outH, float* __restrict__ outF, int relu) {
  __shared__ u16 smem[24576];                 // As[3][128][32] | Bs[3][128][32]
  u16* As = smem;
  u16* Bs = smem + 12288;
  const int tid = threadIdx.x, lane = tid & 63, wv = tid >> 6;
  const int quad = lane >> 4, l16 = lane & 15;
  const int m0 = blockIdx.x * 128, n0 = blockIdx.y * 128;
  const int wm = (wv & 1) * 64, wn = (wv >> 1) * 64;

  const int lrow = lane >> 2;                        // within-group row 0..15
  const int lchunk = (lane & 3) ^ ((lane >> 3) & 3); // swizzled source chunk

  f32x4 acc[4][4];
#pragma unroll
  for (int i = 0; i < 4; i++)
#pragma unroll
    for (int j = 0; j < 4; j++) acc[i][j] = (f32x4){0.f, 0.f, 0.f, 0.f};

  auto stage = [&](int sel, int k0) {                // 4 VMEM ops per call
#pragma unroll
    for (int j = 0; j < 2; j++) {
      int rid = wv * 2 + j;                    // 8 groups of 16 rows
      int r = rid * 16 + lrow;
      load_lds_16(A + (size_t)(m0 + r) * K + k0 + lchunk * 8, &As[sel * 4096 + rid * 512]);
      load_lds_16(Bt + (size_t)(n0 + r) * K + k0 + lchunk * 8, &Bs[sel * 4096 + rid * 512]);
    }
  };

  const int NK = K >> 5;                       // 12 at both call sites
  stage(0, 0);
  stage(1, 32);
  asm volatile("s_waitcnt vmcnt(4)" ::: "memory");   // buf0 ready, buf1 in flight
  __builtin_amdgcn_s_barrier();

  const int slot = (quad ^ ((l16 >> 1) & 3)) * 8;    // un-swizzle for fragment read
  int cur = 0, stg = 2;
  for (int kt = 0; kt < NK; kt++) {
    const bool pf = (kt + 2 < NK);
    if (pf) {
      stage(stg, (kt + 2) * 32);
      if (++stg == 3) stg = 0;
    }
    const u16* Ab = As + cur * 4096;
    const u16* Bb = Bs + cur * 4096;
    bf16x8 af[4], bfr[4];
#pragma unroll
    for (int i = 0; i < 4; i++) af[i]  = *(const bf16x8*)&Ab[(wm + i * 16 + l16) * 32 + slot];
#pragma unroll
    for (int j = 0; j < 4; j++) bfr[j] = *(const bf16x8*)&Bb[(wn + j * 16 + l16) * 32 + slot];
#pragma unroll
    for (int i = 0; i < 4; i++)
#pragma unroll
      for (int j = 0; j < 4; j++)
        acc[i][j] = __builtin_amdgcn_mfma_f32_16x16x32_bf16(af[i], bfr[j], acc[i][j], 0, 0, 0);
    if (pf) asm volatile("s_waitcnt vmcnt(4)" ::: "memory");  // retire buf kt+1's loads
    else    asm volatile("s_waitcnt vmcnt(0)" ::: "memory");  // tail: drain remainder
    __builtin_amdgcn_s_barrier();
    if (++cur == 3) cur = 0;
  }

  if (outH) {
#pragma unroll
    for (int p = 0; p < 4; p++) {
      if (p) __syncthreads();
      if ((wv >> 1) == (p >> 1)) {
#pragma unroll
        for (int jj = 0; jj < 2; jj++) {
          int j = (p & 1) * 2 + jj;
          int gn = n0 + wn + j * 16 + l16;
          float bv = bias ? bias[gn] : 0.f;
          int lcol = jj * 16 + l16;
#pragma unroll
          for (int i = 0; i < 4; i++)
#pragma unroll
            for (int r = 0; r < 4; r++) {
              float v = acc[i][j][r] + bv;
              if (relu) v = fmaxf(v, 0.f);
              smem[(wm + i * 16 + quad * 4 + r) * 36 + lcol] = f2bf(v);
            }
        }
      }
      __syncthreads();
      const int gc0 = n0 + p * 32;
#pragma unroll
      for (int s = 0; s < 4; s++) {
        int row = s * 32 + (tid >> 3);
        int seg = (tid & 7) * 4;
        u16 pk[4];
        *(uint2*)pk = *(const uint2*)&smem[row * 36 + seg];
        size_t o = (size_t)(m0 + row) * Nstore + gc0 + seg;
        if (resid) {
          u16 rv[4];
          *(uint2*)rv = *(const uint2*)&resid[o];
#pragma unroll
          for (int q2 = 0; q2 < 4; q2++) pk[q2] = f2bf(bf2f(pk[q2]) + bf2f(rv[q2]));
        }
        *(uint2*)&outH[o] = *(uint2*)pk;
      }
    }
  } else {
#pragma unroll
    for (int j = 0; j < 4; j++) {
      const int gn = n0 + wn + j * 16 + l16;
      if (gn < Nstore) {
        const float bv = bias ? bias[gn] : 0.f;
#pragma unroll
        for (int i = 0; i < 4; i++)
#pragma unroll
          for (int r = 0; r < 4; r++) {
            const int gm = m0 + wm + i * 16 + quad * 4 + r;
            outF[(size_t)gm * Nstore + gn] = acc[i][j][r] + bv;
          }
      }
    }
  }
}

// ---------------- fused causal attention (load-balanced, bank-swizzled) ----------------
// Wave w owns Q-tiles {w, 15-w} (16 rows each): causal work = exactly 5 tile-chunks per
// wave (was 2..8 -> barrier-bound at 8). Kc/Vtc/P stored with chunk-XOR swizzle
// (slot = chunk ^ key(row)) -> conflict-free writes AND b128 reads, 16B alignment kept.
__global__ __launch_bounds__(512) void attn_k(const u16* __restrict__ qkv,
                                              u16* __restrict__ att) {
  __shared__ u16 Kc[64 * 64];    // K chunk  [s][d],  slot = (d>>3) ^ (s&7) ^ ((s>>3)&7)
  __shared__ u16 Vtc[64 * 64];   // V^T chunk [d][s], slot = (s>>3) ^ (d&7) ^ ((d>>3)&7)
  __shared__ u16 Pl[8 * 16 * 64];// per-wave P [16][64], slot = ch ^ (row>>2 | (row&1)<<2)
  const int b = blockIdx.x / NH, h = blockIdx.x % NH;
  const int tid = threadIdx.x, lane = tid & 63, w = tid >> 6;
  const int quad = lane >> 4, l16 = lane & 15;
  const int rowb = b * T_SEQ;
  const int tiles[2] = {w, 15 - w};

  // Q fragments (A-layout) from global, resident all kernel
  bf16x8 qf[2][2];
#pragma unroll
  for (int ti = 0; ti < 2; ti++)
#pragma unroll
    for (int kk = 0; kk < 2; kk++)
      qf[ti][kk] = *(const bf16x8*)(qkv + (size_t)(rowb + tiles[ti] * 16 + l16) * QKV_N +
                                    h * 64 + kk * 32 + quad * 8);

  f32x4 Oa[2][4];
  float mrun[2][4], lrun[2][4];
#pragma unroll
  for (int ti = 0; ti < 2; ti++) {
#pragma unroll
    for (int di = 0; di < 4; di++) Oa[ti][di] = (f32x4){0.f, 0.f, 0.f, 0.f};
#pragma unroll
    for (int r = 0; r < 4; r++) { mrun[ti][r] = -1e30f; lrun[ti][r] = 0.f; }
  }

  u16* Pw = &Pl[w * 1024];
  const int sr = tid >> 3, sseg = tid & 7;       // sr: s-row 0..63, sseg: 16B chunk 0..7
  const int kst = sseg ^ (sr & 7) ^ ((sr >> 3) & 7);

  for (int c = 0; c < 4; c++) {
    const int s0 = c * 64;
    __syncthreads();                             // WAR
    // stage K chunk (coalesced uint4, swizzled slot)
    *(uint4*)&Kc[sr * 64 + kst * 8] =
        *(const uint4*)(qkv + (size_t)(rowb + s0 + sr) * QKV_N + 384 + h * 64 + sseg * 8);
    // stage V^T chunk (scalar scatter, swizzled slot -> conflict-free)
    {
      union { uint4 u; u16 us[8]; } tb;
      tb.u = *(const uint4*)(qkv + (size_t)(rowb + s0 + sr) * QKV_N + 768 + h * 64 + sseg * 8);
#pragma unroll
      for (int j = 0; j < 8; j++) {
        int d = sseg * 8 + j;
        int vst = (sr >> 3) ^ (d & 7) ^ ((d >> 3) & 7);
        Vtc[d * 64 + vst * 8 + (sr & 7)] = tb.us[j];
      }
    }
    __syncthreads();                             // RAW

    bf16x8 kf[4][2], vf[4][2];
    bool loaded = false;
#pragma unroll
    for (int ti = 0; ti < 2; ti++) {
      const int t = tiles[ti];
      if (t < 4 * c) continue;                   // causal: tile needs chunks 0..t/4
      if (!loaded) {
        loaded = true;
#pragma unroll
        for (int ni = 0; ni < 4; ni++)
#pragma unroll
          for (int kk = 0; kk < 2; kk++) {
            int srow = ni * 16 + l16;
            int ks = (kk * 4 + quad) ^ (srow & 7) ^ ((srow >> 3) & 7);
            kf[ni][kk] = *(const bf16x8*)&Kc[srow * 64 + ks * 8];
            int drow = ni * 16 + l16;            // same index math for V^T rows
            int vs = (kk * 4 + quad) ^ (drow & 7) ^ ((drow >> 3) & 7);
            vf[ni][kk] = *(const bf16x8*)&Vtc[drow * 64 + vs * 8];
          }
      }
      // S = Q K^T
      f32x4 S[4];
#pragma unroll
      for (int ni = 0; ni < 4; ni++) {
        f32x4 z = (f32x4){0.f, 0.f, 0.f, 0.f};
        z = __builtin_amdgcn_mfma_f32_16x16x32_bf16(qf[ti][0], kf[ni][0], z, 0, 0, 0);
        S[ni] = __builtin_amdgcn_mfma_f32_16x16x32_bf16(qf[ti][1], kf[ni][1], z, 0, 0, 0);
      }
      const bool diag = ((t >> 2) == c);
#pragma unroll
      for (int ni = 0; ni < 4; ni++)
#pragma unroll
        for (int r = 0; r < 4; r++) {
          float xv = S[ni][r] * 0.125f;          // DH^-0.5
          if (diag) {
            int trow = t * 16 + quad * 4 + r;
            int s = s0 + ni * 16 + l16;
            if (s > trow) xv = -1e30f;
          }
          S[ni][r] = xv;
        }
      // online softmax (row in 16 lanes of one quad)
#pragma unroll
      for (int r = 0; r < 4; r++) {
        float mx = fmaxf(fmaxf(S[0][r], S[1][r]), fmaxf(S[2][r], S[3][r]));
        mx = fmaxf(mx, __shfl_xor(mx, 1));
        mx = fmaxf(mx, __shfl_xor(mx, 2));
        mx = fmaxf(mx, __shfl_xor(mx, 4));
        mx = fmaxf(mx, __shfl_xor(mx, 8));
        float mnew = fmaxf(mrun[ti][r], mx);
        float alpha = __expf(mrun[ti][r] - mnew);
        float ls = 0.f;
#pragma unroll
        for (int ni = 0; ni < 4; ni++) {
          float p = __expf(S[ni][r] - mnew);
          S[ni][r] = p; ls += p;
        }
        ls += __shfl_xor(ls, 1); ls += __shfl_xor(ls, 2);
        ls += __shfl_xor(ls, 4); ls += __shfl_xor(ls, 8);
        lrun[ti][r] = lrun[ti][r] * alpha + ls;
        mrun[ti][r] = mnew;
#pragma unroll
        for (int di = 0; di < 4; di++) Oa[ti][di][r] *= alpha;
      }
      // P -> per-wave LDS (C-layout write, swizzle key = row>>2 | (row&1)<<2)
#pragma unroll
      for (int ni = 0; ni < 4; ni++)
#pragma unroll
        for (int r = 0; r < 4; r++) {
          int ch = 2 * ni + (l16 >> 3);
          int st = ch ^ (quad | ((r & 1) << 2));
          Pw[(quad * 4 + r) * 64 + st * 8 + (l16 & 7)] = f2bf(S[ni][r]);
        }
      // A-layout read-back (compiler inserts lgkmcnt wait; wave-private, no barrier)
      bf16x8 pf[2];
#pragma unroll
      for (int kk = 0; kk < 2; kk++) {
        int key = (l16 >> 2) | ((l16 & 1) << 2);
        int st = (kk * 4 + quad) ^ key;
        pf[kk] = *(const bf16x8*)&Pw[l16 * 64 + st * 8];
      }
      // O += P V
#pragma unroll
      for (int di = 0; di < 4; di++) {
        Oa[ti][di] = __builtin_amdgcn_mfma_f32_16x16x32_bf16(pf[0], vf[di][0], Oa[ti][di], 0, 0, 0);
        Oa[ti][di] = __builtin_amdgcn_mfma_f32_16x16x32_bf16(pf[1], vf[di][1], Oa[ti][di], 0, 0, 0);
      }
    }
  }

  // normalize + store
#pragma unroll
  for (int ti = 0; ti < 2; ti++)
#pragma unroll
    for (int r = 0; r < 4; r++) {
      float inv = 1.f / lrun[ti][r];
      int trow = tiles[ti] * 16 + quad * 4 + r;
#pragma unroll
      for (int di = 0; di < 4; di++)
        att[(size_t)(rowb + trow) * E_DIM + h * 64 + di * 16 + l16] = f2bf(Oa[ti][di][r] * inv);
    }
}

// ---------------- loss: grid-stride, 1 atomic per block ----------------
__global__ __launch_bounds__(256) void loss_k(const float* __restrict__ logits,
                                              const int* __restrict__ tgt,
                                              float* __restrict__ loss) {
  __shared__ float part[4];
  const int tid = threadIdx.x, lane = tid & 63, w = tid >> 6;
  const int wave_id = blockIdx.x * 4 + w;          // 512 blocks -> 2048 waves
  float acc = 0.f;
  for (int t = wave_id; t < BT; t += 2048) {
    const float* row = logits + (size_t)t * VOC;
    float a = row[lane];
    float b = (lane == 0) ? row[64] : -1e30f;
    float mx = fmaxf(a, b);
#pragma unroll
    for (int d = 1; d < 64; d <<= 1) mx = fmaxf(mx, __shfl_xor(mx, d));
    float sum = __expf(a - mx) + ((lane == 0) ? __expf(b - mx) : 0.f);
#pragma unroll
    for (int d = 1; d < 64; d <<= 1) sum += __shfl_xor(sum, d);
    if (lane == 0) acc += mx + __logf(sum) - row[tgt[t]];
  }
  if (lane == 0) part[w] = acc;
  __syncthreads();
  if (tid == 0)
    atomicAdd(loss, (part[0] + part[1] + part[2] + part[3]) * (1.f / (float)BT));
}

// ---------------- host ----------------
extern "C" void kernel_launch(void* const* d_in, const int* in_sizes, int n_in,
                              void* d_out, int out_size, void* d_ws, size_t ws_size,
                              hipStream_t stream) {
  (void)in_sizes; (void)n_in; (void)out_size; (void)ws_size;
  const int*   idx  = (const int*)d_in[0];
  const int*   tgt  = (const int*)d_in[1];
  const float* tok  = (const float*)d_in[2];
  const float* pos  = (const float*)d_in[3];
  const float* Wq   = (const float*)d_in[4];
  const float* Wk   = (const float*)d_in[5];
  const float* Wv   = (const float*)d_in[6];
  const float* Wo   = (const float*)d_in[7];
  const float* bo   = (const float*)d_in[8];
  const float* ln1s = (const float*)d_in[9];
  const float* ln1b = (const float*)d_in[10];
  const float* ln2s = (const float*)d_in[11];
  const float* ln2b = (const float*)d_in[12];
  const float* W1   = (const float*)d_in[13];
  const float* b1   = (const float*)d_in[14];
  const float* W2   = (const float*)d_in[15];
  const float* b2   = (const float*)d_in[16];
  const float* lnfs = (const float*)d_in[17];
  const float* lnfb = (const float*)d_in[18];
  const float* Wout = (const float*)d_in[19];
  const float* bout = (const float*)d_in[20];

  char* w = (char*)d_ws;
  u16* x      = (u16*)w;    w += (size_t)BT * E_DIM * 2;      // bf16 residual stream
  u16* hb     = (u16*)w;    w += (size_t)BT * E_DIM * 2;
  u16* attb   = (u16*)w;    w += (size_t)BT * E_DIM * 2;
  u16* big    = (u16*)w;    w += (size_t)BT * FF_DIM * 2;     // qkv / ff union
  u16* Wqkv_t = (u16*)w;    w += (size_t)NL * QKV_N * E_DIM * 2;
  u16* Wo_t   = (u16*)w;    w += (size_t)NL * E_DIM * E_DIM * 2;
  u16* W1_t   = (u16*)w;    w += (size_t)NL * FF_DIM * E_DIM * 2;
  u16* W2_t   = (u16*)w;    w += (size_t)NL * E_DIM * FF_DIM * 2;
  u16* Wout_t = (u16*)w;    w += (size_t)128 * E_DIM * 2;
  u16* qkv = big;
  u16* ff  = big;

  float* logits = (float*)d_out;
  float* loss   = logits + (size_t)BT * VOC;

  hipMemsetAsync(Wout_t, 0, 128 * E_DIM * 2, stream);
  transpose_t<<<dim3(12, 2, 36), 256, 0, stream>>>(Wq, Wqkv_t, 384, 64,
      24576, 442368, 6, 24576, 0);
  transpose_t<<<dim3(12, 2, 36), 256, 0, stream>>>(Wk, Wqkv_t, 384, 64,
      24576, 442368, 6, 24576, (long)384 * 384);
  transpose_t<<<dim3(12, 2, 36), 256, 0, stream>>>(Wv, Wqkv_t, 384, 64,
      24576, 442368, 6, 24576, (long)768 * 384);
  transpose_t<<<dim3(12, 12, 6), 256, 0, stream>>>(Wo, Wo_t, 384, 384,
      147456, 147456, 1, 0, 0);
  transpose_t<<<dim3(12, 48, 6), 256, 0, stream>>>(W1, W1_t, 384, 1536,
      589824, 589824, 1, 0, 0);
  transpose_t<<<dim3(48, 12, 6), 256, 0, stream>>>(W2, W2_t, 1536, 384,
      589824, 589824, 1, 0, 0);
  transpose_t<<<dim3(12, 3, 1), 256, 0, stream>>>(Wout, Wout_t, 384, 65,
      0, 0, 1, 0, 0);

  embed_k<<<6144, 256, 0, stream>>>(idx, tok, pos, x);

  for (int l = 0; l < NL; l++) {
    ln_k<<<8192, 256, 0, stream>>>(x, ln1s + l * E_DIM, ln1b + l * E_DIM, hb);
    gemm_p<<<dim3(256, 9), 256, 0, stream>>>(hb, Wqkv_t + (size_t)l * QKV_N * E_DIM,
                                             384, QKV_N, nullptr, nullptr, qkv, nullptr, 0);
    attn_k<<<768, 512, 0, stream>>>(qkv, attb);
    gemm_d<<<dim3(256, 3), 256, 0, stream>>>(attb, Wo_t + (size_t)l * E_DIM * E_DIM,
                                             384, E_DIM, bo + l * E_DIM, x, x, nullptr, 0);
    ln_k<<<8192, 256, 0, stream>>>(x, ln2s + l * E_DIM, ln2b + l * E_DIM, hb);
    gemm_p<<<dim3(256, 12), 256, 0, stream>>>(hb, W1_t + (size_t)l * FF_DIM * E_DIM,
                                              384, FF_DIM, b1 + l * FF_DIM, nullptr, ff, nullptr, 1);
    gemm_d<<<dim3(256, 3), 256, 0, stream>>>(ff, W2_t + (size_t)l * E_DIM * FF_DIM,
                                             1536, E_DIM, b2 + l * E_DIM, x, x, nullptr, 0);
  }
  ln_k<<<8192, 256, 0, stream>>>(x, lnfs, lnfb, hb);
  gemm_d<<<dim3(256, 1), 256, 0, stream>>>(hb, Wout_t, 384, VOC, bout, nullptr, nullptr, logits, 0);

  hipMemsetAsync(loss, 0, 4, stream);
  loss_k<<<512, 256, 0, stream>>>(logits, tgt, loss);
}